// Round 16
// baseline (279.493 us; speedup 1.0000x reference)
//
#include <hip/hip_runtime.h>

typedef __bf16 bf16;
typedef __bf16 bf16x4 __attribute__((ext_vector_type(4)));
typedef __bf16 bf16x8 __attribute__((ext_vector_type(8)));
typedef float f32x4 __attribute__((ext_vector_type(4)));
typedef float f32x16 __attribute__((ext_vector_type(16)));

#define MFMA16(a, b, c) __builtin_amdgcn_mfma_f32_16x16x32_bf16((a), (b), (c), 0, 0, 0)
#define MFMA32(a, b, c) __builtin_amdgcn_mfma_f32_32x32x16_bf16((a), (b), (c), 0, 0, 0)

// B=256, T=320, C=1024, H=64;  M = B*T = 81920
// ws (bf16): Wt [3][64][1024] | Qw [81920][64] | Kw [81920][64] | Vt [256][64][320]

// ---------------- Kernel 0: W -> Wt (bf16, [mat][h][k]) ----------------
__global__ __launch_bounds__(256) void wtrans_kernel(
    const float* __restrict__ Wk, const float* __restrict__ Wq,
    const float* __restrict__ Wv, bf16* __restrict__ Wt) {
  __shared__ bf16 tile[64][65];
  const int mat = blockIdx.x >> 4;
  const int kt = (blockIdx.x & 15) << 6;
  const float* __restrict__ W = (mat == 0) ? Wk : ((mat == 1) ? Wq : Wv);
  const int tid = threadIdx.x;
#pragma unroll
  for (int j = 0; j < 16; ++j) {
    const int i = tid + 256 * j;
    const int k = i >> 6, h = i & 63;
    tile[h][k] = (bf16)W[(kt + k) * 64 + h];
  }
  __syncthreads();
#pragma unroll
  for (int j = 0; j < 16; ++j) {
    const int i = tid + 256 * j;
    const int h = i >> 6, k = i & 63;
    Wt[mat * 65536 + h * 1024 + kt + k] = tile[h][k];
  }
}

// ---------------- Kernel 1: QKV projection, barrier-free 1-wave blocks ----------------
// R15 diagnosis: the per-step vmcnt+barrier lockstep was the cost (R15's 2x
// barriers = -43us; R11: all pipes <30% busy). This version has NO barriers,
// NO main-loop LDS, NO hand waitcnt: 1 wave per block owns 32 rows x 192 cols
// via 32x32x16 MFMA (6 acc frags, 96 VGPR). x A-frags per-lane from HBM;
// W B-frags per-lane from L2-resident Wt (16B contiguous; 32x32 halves W
// traffic to ~1GB L2 = hidden under x's 53us HBM stream). Compiler pipelines.
// A/B frag: idx = lane&31, k = (lane>>5)*8+i. C/D (m74/m101): col = lane&31,
// row = (e&3) + 8*(e>>2) + 4*(lane>>5).
__global__ __launch_bounds__(64) void qkv_kernel(
    const float* __restrict__ x, const bf16* __restrict__ Wt,
    bf16* __restrict__ Qw, bf16* __restrict__ Kw, bf16* __restrict__ Vt) {
  __shared__ __align__(16) bf16 Cs[192 * 40];  // 15 KB, wave-private epilogue
  const int l = threadIdx.x;
  const int m0 = blockIdx.x * 32;  // 32 | 320: strip stays in one batch
  const int row = l & 31, kg = l >> 5;

  f32x16 acc[6];
#pragma unroll
  for (int nf = 0; nf < 6; ++nf) acc[nf] = (f32x16)0.0f;

  const float* xp = x + (size_t)(m0 + row) * 1024 + kg * 8;
  const bf16* wp[6];
#pragma unroll
  for (int nf = 0; nf < 6; ++nf)
    wp[nf] = Wt + (nf >> 1) * 65536 + ((nf & 1) * 32 + row) * 1024 + kg * 8;

#pragma unroll 2
  for (int ks = 0; ks < 64; ++ks) {
    const f32x4 xa = *(const f32x4*)(xp);
    const f32x4 xb = *(const f32x4*)(xp + 4);
    bf16x8 a;
#pragma unroll
    for (int i = 0; i < 4; ++i) {
      a[i] = (bf16)xa[i];
      a[4 + i] = (bf16)xb[i];
    }
#pragma unroll
    for (int nf = 0; nf < 6; ++nf) {
      const bf16x8 b = *(const bf16x8*)(wp[nf]);
      acc[nf] = MFMA32(a, b, acc[nf]);
      wp[nf] += 16;
    }
    xp += 16;
  }

  // ---- epilogue: C -> wave-private LDS transposed -> coalesced stores ----
  // Cs[col:192][row:32, pad 40]: bank stride 20 -> 2-way on writes (ok).
#pragma unroll
  for (int nf = 0; nf < 6; ++nf)
#pragma unroll
    for (int q = 0; q < 4; ++q) {
      bf16x4 o;
#pragma unroll
      for (int r = 0; r < 4; ++r) o[r] = (bf16)acc[nf][q * 4 + r];
      // rows 8q+4kg .. +3 of col nf*32+row
      *(bf16x4*)(Cs + (nf * 32 + row) * 40 + 8 * q + 4 * kg) = o;
    }
  // same-wave LDS RAW: compiler inserts lgkmcnt; no barrier needed (1 wave)

  // K, Q: thread (r = l>>1, c = l&1) writes 64 B contiguous per matrix
  const int r = l >> 1, c = l & 1;
#pragma unroll
  for (int m = 0; m < 2; ++m) {
    bf16* __restrict__ dst = ((m == 0) ? Kw : Qw) + (size_t)(m0 + r) * 64 + c * 32;
    const int cb = m * 64 + c * 32;
#pragma unroll
    for (int v = 0; v < 4; ++v) {
      bf16x8 o;
#pragma unroll
      for (int s = 0; s < 8; ++s) o[s] = Cs[(cb + v * 8 + s) * 40 + r];
      *(bf16x8*)(dst + v * 8) = o;
    }
  }
  // V: thread l -> h = l; 64 B contiguous read (col 128+l) and write
  {
    const int bb = m0 / 320, tt0 = m0 % 320;
    const bf16* src = Cs + (128 + l) * 40;
    bf16* __restrict__ dst = Vt + ((size_t)bb * 64 + l) * 320 + tt0;
#pragma unroll
    for (int v = 0; v < 4; ++v)
      *(bf16x8*)(dst + v * 8) = *(const bf16x8*)(src + v * 8);
  }
}

// ---------------- Kernel 2: causal attention (frozen, round-6 version) ----------------
template <int QT>
__device__ __forceinline__ void attn_impl(
    int b, const bf16* __restrict__ Qw, const bf16* __restrict__ Kw,
    const bf16* __restrict__ Vt, float* __restrict__ out,
    char* Ks, char* Vs, char* Ps) {
  constexpr int NT = QT + 1;  // 64-wide s-tiles
  const int tid = threadIdx.x;
  const int w = tid >> 6, l = tid & 63;
  const int lr = l & 15, lg = l >> 4;
  const int t0 = QT * 64 + w * 16;
  const int tq = t0 + lr;

  const bf16* qp = Qw + ((size_t)b * 320 + tq) * 64 + lg * 8;
  const bf16x8 bq0 = *(const bf16x8*)qp;
  const bf16x8 bq1 = *(const bf16x8*)(qp + 32);

  f32x4 acc[NT * 4];
#pragma unroll
  for (int i = 0; i < NT * 4; ++i) acc[i] = (f32x4)0.0f;

  bf16x8 kg0, kg1;
  const int krow = w * 16 + (l >> 2);
  const int kcb = (l & 3) * 16;
  const int ksw = (krow & 7) << 4;
  auto gloadK = [&](int st) {
    const bf16* src = Kw + ((size_t)b * 320 + st * 64 + krow) * 64 + (l & 3) * 8;
    kg0 = *(const bf16x8*)src;
    kg1 = *(const bf16x8*)(src + 32);
  };
  auto dswriteK = [&](int buf) {
    char* base = Ks + buf * 8192 + krow * 128;
    *(bf16x8*)(base + (kcb ^ ksw)) = kg0;
    *(bf16x8*)(base + ((kcb + 64) ^ ksw)) = kg1;
  };

  gloadK(0);
  dswriteK(0);
  asm volatile("s_waitcnt lgkmcnt(0)" ::: "memory");
  __builtin_amdgcn_s_barrier();

  const int asw = (lr & 7) << 4;
#pragma unroll
  for (int st = 0; st < NT; ++st) {
    if (st < QT) gloadK(st + 1);
    const char* kb = Ks + (st & 1) * 8192;
#pragma unroll
    for (int nf = 0; nf < 4; ++nf) {
      const char* rp = kb + (nf * 16 + lr) * 128;
      const bf16x8 a0 = *(const bf16x8*)(rp + ((lg * 16) ^ asw));
      const bf16x8 a1 = *(const bf16x8*)(rp + ((64 + lg * 16) ^ asw));
      acc[st * 4 + nf] = MFMA16(a0, bq0, acc[st * 4 + nf]);
      acc[st * 4 + nf] = MFMA16(a1, bq1, acc[st * 4 + nf]);
    }
    if (st < QT) {
      dswriteK((st + 1) & 1);
      asm volatile("s_waitcnt lgkmcnt(0)" ::: "memory");
      __builtin_amdgcn_s_barrier();
    }
  }

  uint2 vg[4];
  const int vrow = w * 16 + (l >> 4);
  auto gloadV = [&](int st) {
    const bf16* src = Vt + ((size_t)b * 64 + vrow) * 320 + st * 64 + (l & 15) * 4;
#pragma unroll
    for (int i = 0; i < 4; ++i) vg[i] = *(const uint2*)(src + i * 4 * 320);
  };
  auto dswriteV = [&](int buf) {
#pragma unroll
    for (int i = 0; i < 4; ++i) {
      const int hl = vrow + i * 4;
      *(uint2*)(Vs + buf * 8192 + hl * 128 + (((l & 15) * 8) ^ ((hl & 7) << 4))) = vg[i];
    }
  };
  gloadV(0);

  float mx = -1e30f;
#pragma unroll
  for (int st = 0; st < NT; ++st)
#pragma unroll
    for (int nf = 0; nf < 4; ++nf)
#pragma unroll
      for (int r = 0; r < 4; ++r) {
        const int sg = st * 64 + nf * 16 + lg * 4 + r;
        float v = acc[st * 4 + nf][r] * 0.03125f;
        v = (sg > tq) ? -1e30f : v;
        acc[st * 4 + nf][r] = v;
        mx = fmaxf(mx, v);
      }
  mx = fmaxf(mx, __shfl_xor(mx, 16));
  mx = fmaxf(mx, __shfl_xor(mx, 32));
  float sum = 0.f;
#pragma unroll
  for (int i = 0; i < NT * 4; ++i)
#pragma unroll
    for (int r = 0; r < 4; ++r) {
      const float p = __expf(acc[i][r] - mx);
      acc[i][r] = p;
      sum += p;
    }
  sum += __shfl_xor(sum, 16);
  sum += __shfl_xor(sum, 32);
  const float rinv = 1.0f / sum;

  dswriteV(0);
  asm volatile("s_waitcnt lgkmcnt(0)" ::: "memory");
  __builtin_amdgcn_s_barrier();

  char* Pw = Ps + w * 2048;
  f32x4 ao[4];
#pragma unroll
  for (int hf = 0; hf < 4; ++hf) ao[hf] = (f32x4)0.0f;

#pragma unroll
  for (int st = 0; st < NT; ++st) {
    if (st < QT) gloadV(st + 1);
#pragma unroll
    for (int nf = 0; nf < 4; ++nf) {
      bf16x4 o;
#pragma unroll
      for (int r = 0; r < 4; ++r) o[r] = (bf16)(acc[st * 4 + nf][r] * rinv);
      *(bf16x4*)(Pw + lr * 128 + ((nf * 32 + lg * 8) ^ asw)) = o;
    }
    const char* vb = Vs + (st & 1) * 8192;
#pragma unroll
    for (int ks = 0; ks < 2; ++ks) {
      const bf16x8 ap = *(const bf16x8*)(Pw + lr * 128 + ((ks * 64 + lg * 16) ^ asw));
#pragma unroll
      for (int hf = 0; hf < 4; ++hf) {
        const bf16x8 bv =
            *(const bf16x8*)(vb + (hf * 16 + lr) * 128 + ((ks * 64 + lg * 16) ^ asw));
        ao[hf] = MFMA16(ap, bv, ao[hf]);
      }
    }
    if (st < QT) {
      dswriteV((st + 1) & 1);
      asm volatile("s_waitcnt lgkmcnt(0)" ::: "memory");
      __builtin_amdgcn_s_barrier();
    }
  }

  const int rowb = t0 + lg * 4;
#pragma unroll
  for (int hf = 0; hf < 4; ++hf)
#pragma unroll
    for (int r = 0; r < 4; ++r)
      out[((size_t)b * 320 + rowb + r) * 64 + hf * 16 + lr] = ao[hf][r];
}

__global__ __launch_bounds__(256) void attn_kernel(
    const bf16* __restrict__ Qw, const bf16* __restrict__ Kw,
    const bf16* __restrict__ Vt, float* __restrict__ out) {
  __shared__ __align__(16) char Ks[2 * 8192];
  __shared__ __align__(16) char Vs[2 * 8192];
  __shared__ __align__(16) char Ps[4 * 2048];
  const int b = blockIdx.x;
  const int qt = 4 - blockIdx.y;  // heavy blocks dispatch first
  switch (qt) {
    case 0: attn_impl<0>(b, Qw, Kw, Vt, out, Ks, Vs, Ps); break;
    case 1: attn_impl<1>(b, Qw, Kw, Vt, out, Ks, Vs, Ps); break;
    case 2: attn_impl<2>(b, Qw, Kw, Vt, out, Ks, Vs, Ps); break;
    case 3: attn_impl<3>(b, Qw, Kw, Vt, out, Ks, Vs, Ps); break;
    default: attn_impl<4>(b, Qw, Kw, Vt, out, Ks, Vs, Ps); break;
  }
}

extern "C" void kernel_launch(void* const* d_in, const int* in_sizes, int n_in,
                              void* d_out, int out_size, void* d_ws, size_t ws_size,
                              hipStream_t stream) {
  const float* x  = (const float*)d_in[0];
  const float* Wk = (const float*)d_in[1];
  const float* Wq = (const float*)d_in[2];
  const float* Wv = (const float*)d_in[3];
  float* out = (float*)d_out;

  bf16* Wt = (bf16*)d_ws;
  bf16* Qw = Wt + 3 * 64 * 1024;
  bf16* Kw = Qw + (size_t)81920 * 64;
  bf16* Vt = Kw + (size_t)81920 * 64;

  hipLaunchKernelGGL(wtrans_kernel, dim3(48), dim3(256), 0, stream, Wk, Wq, Wv, Wt);
  hipLaunchKernelGGL(qkv_kernel, dim3(2560), dim3(64), 0, stream, x, Wt, Qw, Kw, Vt);
  hipLaunchKernelGGL(attn_kernel, dim3(256, 5), dim3(256), 0, stream, Qw, Kw, Vt, out);
}